// Round 5
// baseline (100.183 us; speedup 1.0000x reference)
//
#include <hip/hip_runtime.h>
#include <hip/hip_bf16.h>

// QuantumFeedForward, fully fused:
//   q[n,w]  = prod_{v in M_w} cos(theta_v)*cos(x[n,v])      (analytic circuit collapse)
//   out     = relu(q@W1^T+b1) @ W2^T + b2
// One MFMA kernel generates each H k-tile on the fly while MFMA consumes the previous
// tile. W1/b1 per-step slices are REGISTER-prefetched (22 float4 global loads issued
// before the MFMA phase, consumed after it) -> HGEN is pure register math, no LDS
// reads. W2b is CHUNK-SWIZZLED in global (chunk c of row r at (c&~7)|((c&7)^(r&7)))
// so linear global_load_lds yields a conflict-free XOR-swizzled LDS tile.

typedef __attribute__((ext_vector_type(8))) short bf16x8;
typedef __attribute__((ext_vector_type(4))) float f32x4;
typedef __attribute__((ext_vector_type(2))) float f32x2;
typedef __attribute__((ext_vector_type(8))) unsigned short us8;

#define NTOK  16384
#define EMBED 512
#define FFN   2048
#define NQ    10
#define BM    128
#define BN    256
#define BK    64
#define NT    (FFN / BK)   // 32

__device__ __forceinline__ unsigned short f2bf(float f) {
  union { float f; unsigned int u; } a; a.f = f;
  unsigned int r = a.u + 0x7FFFu + ((a.u >> 16) & 1u);   // RNE
  return (unsigned short)(r >> 16);
}

__device__ __forceinline__ void gload_lds16(const void* g, void* l) {
  __builtin_amdgcn_global_load_lds(
      (const __attribute__((address_space(1))) unsigned int*)g,
      (__attribute__((address_space(3))) unsigned int*)l, 16, 0, 0);
}

// ---------------- K0: W2 (512x2048 f32) -> bf16, chunk-swizzled ----------------
__global__ __launch_bounds__(256) void k_cvt_w2(const float* __restrict__ W2,
                                                unsigned short* __restrict__ W2b) {
  int gid = blockIdx.x * 256 + threadIdx.x;     // one 16B chunk (8 f32 -> 8 bf16)
  int idx = gid * 8;
  int row = idx >> 11;                          // /2048
  int c   = (idx >> 3) & 255;                   // chunk within row
  int sc  = (c & ~7) | ((c & 7) ^ (row & 7));   // swizzled chunk
  float4 v0 = *(const float4*)(W2 + idx);
  float4 v1 = *(const float4*)(W2 + idx + 4);
  us8 o;
  o[0] = f2bf(v0.x); o[1] = f2bf(v0.y); o[2] = f2bf(v0.z); o[3] = f2bf(v0.w);
  o[4] = f2bf(v1.x); o[5] = f2bf(v1.y); o[6] = f2bf(v1.z); o[7] = f2bf(v1.w);
  *(us8*)(W2b + (size_t)row * FFN + sc * 8) = o;
}

// ---------------- K0b: W1 (2048x10) -> W1t (10x2048) f32 ----------------
__global__ __launch_bounds__(256) void k_cvt_w1t(const float* __restrict__ W1,
                                                 float* __restrict__ W1t) {
  int idx = blockIdx.x * 256 + threadIdx.x;     // idx = w*2048+k
  int w = idx >> 11, k = idx & 2047;
  W1t[idx] = W1[k * NQ + w];
}

// ---------------- K1: fused H-gen + GEMM ----------------
__global__ __launch_bounds__(512, 2) void k_fused(const float* __restrict__ x,
                                                  const float* __restrict__ theta,
                                                  const float* __restrict__ W1t,
                                                  const float* __restrict__ b1,
                                                  const unsigned short* __restrict__ W2b,
                                                  const float* __restrict__ b2,
                                                  float* __restrict__ out) {
  __shared__ float qs[BM][NQ];
  __shared__ short Ah[2][BM * BK];       // H tile, XOR-swizzled rows of 128B
  __shared__ short Bw[2][BN * BK];       // W2 tile, swizzle inherited from global

  // XCD-aware bijective swizzle: 256 blocks, 32 consecutive per XCD.
  int bid = blockIdx.x;
  int swz = (bid & 7) * 32 + (bid >> 3);
  const int m0 = (swz >> 1) * BM;
  const int n0 = (swz & 1) * BN;
  const int tid  = threadIdx.x;
  const int lane = tid & 63;
  const int wave = tid >> 6;             // 8 waves: 2 (M) x 4 (N)
  const int wr = wave >> 2, wc = wave & 3;

  // ---- q for this block's 128 tokens ----
  if (tid < BM) {
    const int masks[NQ] = {0x2AB,0x3FD,0x3FA,0x3F5,0x3EA,0x3D5,0x3AA,0x355,0x2AA,0x155};
    float z[NQ];
#pragma unroll
    for (int w = 0; w < NQ; ++w)
      z[w] = __builtin_cosf(x[(size_t)(m0 + tid) * EMBED + w]) * __builtin_cosf(theta[w]);
#pragma unroll
    for (int w = 0; w < NQ; ++w) {
      float p = 1.f;
#pragma unroll
      for (int v = 0; v < NQ; ++v)
        if ((masks[w] >> v) & 1) p *= z[v];
      qs[tid][w] = p;
    }
  }
  __syncthreads();

  // H-gen mapping: thread -> (k-octet, token pair).
  const int oct = tid & 7;               // 8 bf16 columns k = kt*64 + oct*8 ..+7
  const int grp = tid >> 3;              // 64 groups x 2 tokens
  const int t0 = grp * 2, t1 = t0 + 1;
  float q0r[NQ], q1r[NQ];
#pragma unroll
  for (int w = 0; w < NQ; ++w) { q0r[w] = qs[t0][w]; q1r[w] = qs[t1][w]; }

  f32x4 acc[4][4] = {};
  float4 wva[NQ], wvb[NQ], bva, bvb;     // register-prefetched W1/b1 step slice
  f32x2 h0p[4], h1p[4];

#define STAGE_W2(KT, B)                                                         \
  {                                                                             \
    _Pragma("unroll")                                                           \
    for (int p = 0; p < 4; ++p) {                                               \
      int ch = p * 512 + tid;                   /* 2048 chunks = 256r x 8s */   \
      int row = ch >> 3, slot = ch & 7;                                         \
      gload_lds16(&W2b[(size_t)(n0 + row) * FFN + (KT) * BK + slot * 8],        \
                  &Bw[B][ch * 8]);                                              \
    }                                                                           \
  }

  // Issue 22 independent global float4 loads (L2-resident W1t/b1) into registers.
#define WLOAD(KT)                                                               \
  {                                                                             \
    const float* wp = W1t + (KT) * BK + oct * 8;                                \
    _Pragma("unroll")                                                           \
    for (int w = 0; w < NQ; ++w) {                                              \
      wva[w] = *(const float4*)(wp + (size_t)w * FFN);                          \
      wvb[w] = *(const float4*)(wp + (size_t)w * FFN + 4);                      \
    }                                                                           \
    bva = *(const float4*)(b1 + (KT) * BK + oct * 8);                           \
    bvb = *(const float4*)(b1 + (KT) * BK + oct * 8 + 4);                       \
  }

#define HGEN()                                                                  \
  {                                                                             \
    h0p[0] = (f32x2){bva.x, bva.y}; h0p[1] = (f32x2){bva.z, bva.w};             \
    h0p[2] = (f32x2){bvb.x, bvb.y}; h0p[3] = (f32x2){bvb.z, bvb.w};             \
    _Pragma("unroll")                                                           \
    for (int j = 0; j < 4; ++j) h1p[j] = h0p[j];                                \
    _Pragma("unroll")                                                           \
    for (int w = 0; w < NQ; ++w) {                                              \
      f32x2 w0 = {wva[w].x, wva[w].y}, w1v = {wva[w].z, wva[w].w};              \
      f32x2 w2v = {wvb[w].x, wvb[w].y}, w3 = {wvb[w].z, wvb[w].w};              \
      f32x2 a0 = {q0r[w], q0r[w]}, a1 = {q1r[w], q1r[w]};                       \
      h0p[0] += a0 * w0; h0p[1] += a0 * w1v; h0p[2] += a0 * w2v; h0p[3] += a0 * w3; \
      h1p[0] += a1 * w0; h1p[1] += a1 * w1v; h1p[2] += a1 * w2v; h1p[3] += a1 * w3; \
    }                                                                           \
  }

#define HWRITE(B)                                                               \
  {                                                                             \
    us8 o0, o1;                                                                 \
    _Pragma("unroll")                                                           \
    for (int j = 0; j < 4; ++j) {                                               \
      o0[2*j]   = f2bf(fmaxf(h0p[j].x, 0.f));                                   \
      o0[2*j+1] = f2bf(fmaxf(h0p[j].y, 0.f));                                   \
      o1[2*j]   = f2bf(fmaxf(h1p[j].x, 0.f));                                   \
      o1[2*j+1] = f2bf(fmaxf(h1p[j].y, 0.f));                                   \
    }                                                                           \
    *(us8*)&Ah[B][t0 * BK + (oct ^ (t0 & 7)) * 8] = o0;                         \
    *(us8*)&Ah[B][t1 * BK + (oct ^ (t1 & 7)) * 8] = o1;                         \
  }

  // ---- pipeline prologue: tile 0 ----
  WLOAD(0);
  STAGE_W2(0, 0);
  HGEN();
  HWRITE(0);
  __syncthreads();            // drains vmcnt (Bw[0]) + lgkm (Ah[0])

  // ---- main loop ----
  for (int kt = 0; kt < NT; ++kt) {
    const int cur = kt & 1, nxt = cur ^ 1;
    // (1) issue next tile's loads FIRST: W1/b1 -> regs, W2 -> LDS (async)
    if (kt + 1 < NT) {
      WLOAD(kt + 1);
      STAGE_W2(kt + 1, nxt);
    }
    // (2) MFMA on current tile — covers the load latency
#pragma unroll
    for (int kk = 0; kk < 2; ++kk) {
      bf16x8 af[4], bg[4];
#pragma unroll
      for (int i = 0; i < 4; ++i) {
        int row = wr * 64 + i * 16 + (lane & 15);
        int slot = (kk * 4 + (lane >> 4)) ^ (row & 7);
        af[i] = *(const bf16x8*)&Ah[cur][row * BK + slot * 8];
      }
#pragma unroll
      for (int j = 0; j < 4; ++j) {
        int row = wc * 64 + j * 16 + (lane & 15);
        int slot = (kk * 4 + (lane >> 4)) ^ (row & 7);
        bg[j] = *(const bf16x8*)&Bw[cur][row * BK + slot * 8];
      }
      __builtin_amdgcn_s_setprio(1);
#pragma unroll
      for (int i = 0; i < 4; ++i)
#pragma unroll
        for (int j = 0; j < 4; ++j)
          acc[i][j] = __builtin_amdgcn_mfma_f32_16x16x32_bf16(af[i], bg[j], acc[i][j], 0, 0, 0);
      __builtin_amdgcn_s_setprio(0);
    }
    // (3) H for next tile: pure register math, then LDS write
    if (kt + 1 < NT) {
      HGEN();
      HWRITE(nxt);
    }
    __syncthreads();          // one barrier per K-step
  }

  // ---- epilogue: out = acc + b2 ----
#pragma unroll
  for (int i = 0; i < 4; ++i) {
    const int row = m0 + wr * 64 + i * 16 + (lane >> 4) * 4;
#pragma unroll
    for (int j = 0; j < 4; ++j) {
      const int col = n0 + wc * 64 + j * 16 + (lane & 15);
      const float bbv = b2[col];
#pragma unroll
      for (int r = 0; r < 4; ++r)
        out[(size_t)(row + r) * EMBED + col] = acc[i][j][r] + bbv;
    }
  }
#undef STAGE_W2
#undef WLOAD
#undef HGEN
#undef HWRITE
}

extern "C" void kernel_launch(void* const* d_in, const int* in_sizes, int n_in,
                              void* d_out, int out_size, void* d_ws, size_t ws_size,
                              hipStream_t stream) {
  const float* x     = (const float*)d_in[0];
  const float* theta = (const float*)d_in[1];
  const float* W1    = (const float*)d_in[2];
  const float* b1    = (const float*)d_in[3];
  const float* W2    = (const float*)d_in[4];
  const float* b2    = (const float*)d_in[5];
  float* out = (float*)d_out;

  char* ws = (char*)d_ws;
  unsigned short* W2b = (unsigned short*)ws;                 // 2 MB bf16 swizzled
  float* W1t = (float*)(ws + (2u << 20));                    // 80 KB f32 transposed

  k_cvt_w2<<<(EMBED * FFN) / (256 * 8), 256, 0, stream>>>(W2, W2b);
  k_cvt_w1t<<<(NQ * FFN) / 256, 256, 0, stream>>>(W1, W1t);
  k_fused<<<(NTOK / BM) * (EMBED / BN), 512, 0, stream>>>(x, theta, W1t, b1, W2b, b2, out);
}

// Round 6
// 86.690 us; speedup vs baseline: 1.1556x; 1.1556x over previous
//
#include <hip/hip_runtime.h>
#include <hip/hip_bf16.h>

// QuantumFeedForward, fully fused:
//   q[n,w]  = prod_{v in M_w} cos(theta_v)*cos(x[n,v])      (analytic circuit collapse)
//   out     = relu(q@W1^T+b1) @ W2^T + b2
// One MFMA kernel generates each H k-tile on the fly. 128x128 tile, 8 waves,
// LDS 71KB -> 2 blocks/CU (4 waves/SIMD) so wave multiplicity hides the per-step
// latency chains (m114). W1/b1 step-slices LDS-staged at prefetch distance 2;
// HGEN streams them (no register batch -> fits 128 VGPR). W2b is CHUNK-SWIZZLED
// in global (chunk c of row r at (c&~7)|((c&7)^(r&7))) so linear global_load_lds
// yields a conflict-free XOR-swizzled LDS tile (verified: 0 bank conflicts).

typedef __attribute__((ext_vector_type(8))) short bf16x8;
typedef __attribute__((ext_vector_type(4))) float f32x4;
typedef __attribute__((ext_vector_type(2))) float f32x2;
typedef __attribute__((ext_vector_type(8))) unsigned short us8;

#define NTOK  16384
#define EMBED 512
#define FFN   2048
#define NQ    10
#define BM    128
#define BN    128
#define BK    64
#define NT    (FFN / BK)   // 32

__device__ __forceinline__ unsigned short f2bf(float f) {
  union { float f; unsigned int u; } a; a.f = f;
  unsigned int r = a.u + 0x7FFFu + ((a.u >> 16) & 1u);   // RNE
  return (unsigned short)(r >> 16);
}

__device__ __forceinline__ void gload_lds16(const void* g, void* l) {
  __builtin_amdgcn_global_load_lds(
      (const __attribute__((address_space(1))) unsigned int*)g,
      (__attribute__((address_space(3))) unsigned int*)l, 16, 0, 0);
}

// ---------------- K0: W2 (512x2048 f32) -> bf16, chunk-swizzled ----------------
__global__ __launch_bounds__(256) void k_cvt_w2(const float* __restrict__ W2,
                                                unsigned short* __restrict__ W2b) {
  int gid = blockIdx.x * 256 + threadIdx.x;     // one 16B chunk (8 f32 -> 8 bf16)
  int idx = gid * 8;
  int row = idx >> 11;                          // /2048
  int c   = (idx >> 3) & 255;                   // chunk within row
  int sc  = (c & ~7) | ((c & 7) ^ (row & 7));   // swizzled chunk
  float4 v0 = *(const float4*)(W2 + idx);
  float4 v1 = *(const float4*)(W2 + idx + 4);
  us8 o;
  o[0] = f2bf(v0.x); o[1] = f2bf(v0.y); o[2] = f2bf(v0.z); o[3] = f2bf(v0.w);
  o[4] = f2bf(v1.x); o[5] = f2bf(v1.y); o[6] = f2bf(v1.z); o[7] = f2bf(v1.w);
  *(us8*)(W2b + (size_t)row * FFN + sc * 8) = o;
}

// ---------------- K0b: W1 (2048x10) -> W1t (10x2048) f32 ----------------
__global__ __launch_bounds__(256) void k_cvt_w1t(const float* __restrict__ W1,
                                                 float* __restrict__ W1t) {
  int idx = blockIdx.x * 256 + threadIdx.x;     // idx = w*2048+k
  int w = idx >> 11, k = idx & 2047;
  W1t[idx] = W1[k * NQ + w];
}

// ---------------- K1: fused H-gen + GEMM ----------------
__global__ __launch_bounds__(512, 4) void k_fused(const float* __restrict__ x,
                                                  const float* __restrict__ theta,
                                                  const float* __restrict__ W1t,
                                                  const float* __restrict__ b1,
                                                  const unsigned short* __restrict__ W2b,
                                                  const float* __restrict__ b2,
                                                  float* __restrict__ out) {
  __shared__ short Ah[2][BM * BK];       // H tile, XOR-swizzled rows of 128B (32KB)
  __shared__ short Bw[2][BN * BK];       // W2 tile, swizzle from global layout (32KB)
  __shared__ float W1s[2][NQ * BK];      // per-step W1 slice, dist-2 prefetch (5KB)
  __shared__ float b1s[2][BK];           // (0.5KB)  total ~71KB -> 2 blocks/CU

  // XCD-aware bijective swizzle: 512 blocks, 64 consecutive per XCD.
  int bid = blockIdx.x;
  int swz = (bid & 7) * 64 + (bid >> 3);
  const int m0 = (swz >> 2) * BM;
  const int n0 = (swz & 3) * BN;
  const int tid  = threadIdx.x;
  const int lane = tid & 63;
  const int wave = tid >> 6;             // 8 waves: 2 (M) x 4 (N), 64x32 each
  const int wr = wave >> 2, wc = wave & 3;

  // ---- q for this thread's 2 tokens, in registers (no LDS, no extra barrier) ----
  const int oct = tid & 7;               // 8 bf16 columns k = kt*64 + oct*8 ..+7
  const int grp = tid >> 3;              // 64 groups x 2 tokens
  const int t0 = grp * 2, t1 = t0 + 1;
  float q0r[NQ], q1r[NQ];
  {
    const int masks[NQ] = {0x2AB,0x3FD,0x3FA,0x3F5,0x3EA,0x3D5,0x3AA,0x355,0x2AA,0x155};
    float z0[NQ], z1[NQ];
#pragma unroll
    for (int w = 0; w < NQ; ++w) {
      float ct = __builtin_cosf(theta[w]);
      z0[w] = __builtin_cosf(x[(size_t)(m0 + t0) * EMBED + w]) * ct;
      z1[w] = __builtin_cosf(x[(size_t)(m0 + t1) * EMBED + w]) * ct;
    }
#pragma unroll
    for (int w = 0; w < NQ; ++w) {
      float p0 = 1.f, p1 = 1.f;
#pragma unroll
      for (int v = 0; v < NQ; ++v)
        if ((masks[w] >> v) & 1) { p0 *= z0[v]; p1 *= z1[v]; }
      q0r[w] = p0; q1r[w] = p1;
    }
  }

  f32x4 acc[4][2] = {};

#define STAGE_W2(KT, B)                                                         \
  {                                                                             \
    _Pragma("unroll")                                                           \
    for (int p = 0; p < 2; ++p) {                                               \
      int ch = p * 512 + tid;                   /* 1024 chunks = 128r x 8s */   \
      int row = ch >> 3, slot = ch & 7;                                         \
      gload_lds16(&W2b[(size_t)(n0 + row) * FFN + (KT) * BK + slot * 8],        \
                  &Bw[B][ch * 8]);                                              \
    }                                                                           \
  }

  // W1 slice (10 rows x 64 f32) + b1 slice (64 f32) for step KT -> buffer B.
#define STAGE_W1(KT, B)                                                         \
  {                                                                             \
    if (wave < 3) {                                                             \
      int r = wave * 4 + (lane >> 4);                                           \
      if (r < NQ)                                                               \
        gload_lds16(&W1t[(size_t)r * FFN + (KT) * BK + (lane & 15) * 4],        \
                    &W1s[B][wave * 4 * BK]);                                    \
    } else if (wave == 3 && lane < 16) {                                        \
      gload_lds16(&b1[(KT) * BK + lane * 4], &b1s[B][0]);                       \
    }                                                                           \
  }

  // HGEN streams W1s from LDS (latency hidden by 4 waves/SIMD), pure pk-fma math.
#define HGEN_HWRITE(B)                                                          \
  {                                                                             \
    float4 bva = *(const float4*)&b1s[B][oct * 8];                              \
    float4 bvb = *(const float4*)&b1s[B][oct * 8 + 4];                          \
    f32x2 h00 = {bva.x, bva.y}, h01 = {bva.z, bva.w};                           \
    f32x2 h02 = {bvb.x, bvb.y}, h03 = {bvb.z, bvb.w};                           \
    f32x2 h10 = h00, h11 = h01, h12 = h02, h13 = h03;                           \
    _Pragma("unroll")                                                           \
    for (int w = 0; w < NQ; ++w) {                                              \
      float4 wa = *(const float4*)&W1s[B][w * BK + oct * 8];                    \
      float4 wb = *(const float4*)&W1s[B][w * BK + oct * 8 + 4];                \
      f32x2 wv0 = {wa.x, wa.y}, wv1 = {wa.z, wa.w};                             \
      f32x2 wv2 = {wb.x, wb.y}, wv3 = {wb.z, wb.w};                             \
      f32x2 a0 = {q0r[w], q0r[w]}, a1 = {q1r[w], q1r[w]};                       \
      h00 += a0 * wv0; h01 += a0 * wv1; h02 += a0 * wv2; h03 += a0 * wv3;       \
      h10 += a1 * wv0; h11 += a1 * wv1; h12 += a1 * wv2; h13 += a1 * wv3;       \
    }                                                                           \
    h00 = __builtin_elementwise_max(h00, (f32x2)0.f);                           \
    h01 = __builtin_elementwise_max(h01, (f32x2)0.f);                           \
    h02 = __builtin_elementwise_max(h02, (f32x2)0.f);                           \
    h03 = __builtin_elementwise_max(h03, (f32x2)0.f);                           \
    h10 = __builtin_elementwise_max(h10, (f32x2)0.f);                           \
    h11 = __builtin_elementwise_max(h11, (f32x2)0.f);                           \
    h12 = __builtin_elementwise_max(h12, (f32x2)0.f);                           \
    h13 = __builtin_elementwise_max(h13, (f32x2)0.f);                           \
    us8 o0, o1;                                                                 \
    o0[0]=f2bf(h00.x); o0[1]=f2bf(h00.y); o0[2]=f2bf(h01.x); o0[3]=f2bf(h01.y); \
    o0[4]=f2bf(h02.x); o0[5]=f2bf(h02.y); o0[6]=f2bf(h03.x); o0[7]=f2bf(h03.y); \
    o1[0]=f2bf(h10.x); o1[1]=f2bf(h10.y); o1[2]=f2bf(h11.x); o1[3]=f2bf(h11.y); \
    o1[4]=f2bf(h12.x); o1[5]=f2bf(h12.y); o1[6]=f2bf(h13.x); o1[7]=f2bf(h13.y); \
    *(us8*)&Ah[B][t0 * BK + (oct ^ (t0 & 7)) * 8] = o0;                         \
    *(us8*)&Ah[B][t1 * BK + (oct ^ (t1 & 7)) * 8] = o1;                         \
  }

  // ---- pipeline prologue ----
  STAGE_W1(0, 0);
  STAGE_W1(1, 1);
  STAGE_W2(0, 0);
  __syncthreads();            // W1s/b1s[0,1] + Bw[0] ready
  HGEN_HWRITE(0);             // Ah[0]
  __syncthreads();

  // ---- main loop: 2-phase dbuf; occupancy (2 blocks/CU) hides the drains ----
  for (int kt = 0; kt < NT; ++kt) {
    const int cur = kt & 1, nxt = cur ^ 1;
    if (kt + 2 < NT) STAGE_W1(kt + 2, cur);   // W1s[cur] slice consumed last iter
    if (kt + 1 < NT) STAGE_W2(kt + 1, nxt);
#pragma unroll
    for (int kk = 0; kk < 2; ++kk) {
      bf16x8 af[4], bg[2];
#pragma unroll
      for (int i = 0; i < 4; ++i) {
        int row = wr * 64 + i * 16 + (lane & 15);
        int slot = (kk * 4 + (lane >> 4)) ^ (row & 7);
        af[i] = *(const bf16x8*)&Ah[cur][row * BK + slot * 8];
      }
#pragma unroll
      for (int j = 0; j < 2; ++j) {
        int row = wc * 32 + j * 16 + (lane & 15);
        int slot = (kk * 4 + (lane >> 4)) ^ (row & 7);
        bg[j] = *(const bf16x8*)&Bw[cur][row * BK + slot * 8];
      }
      __builtin_amdgcn_s_setprio(1);
#pragma unroll
      for (int i = 0; i < 4; ++i)
#pragma unroll
        for (int j = 0; j < 2; ++j)
          acc[i][j] = __builtin_amdgcn_mfma_f32_16x16x32_bf16(af[i], bg[j], acc[i][j], 0, 0, 0);
      __builtin_amdgcn_s_setprio(0);
    }
    if (kt + 1 < NT) HGEN_HWRITE(nxt);        // reads W1s[nxt] (staged kt-1), writes Ah[nxt]
    __syncthreads();          // one barrier per K-step
  }

  // ---- epilogue: out = acc + b2 ----
#pragma unroll
  for (int i = 0; i < 4; ++i) {
    const int row = m0 + wr * 64 + i * 16 + (lane >> 4) * 4;
#pragma unroll
    for (int j = 0; j < 2; ++j) {
      const int col = n0 + wc * 32 + j * 16 + (lane & 15);
      const float bbv = b2[col];
#pragma unroll
      for (int r = 0; r < 4; ++r)
        out[(size_t)(row + r) * EMBED + col] = acc[i][j][r] + bbv;
    }
  }
#undef STAGE_W2
#undef STAGE_W1
#undef HGEN_HWRITE
}

extern "C" void kernel_launch(void* const* d_in, const int* in_sizes, int n_in,
                              void* d_out, int out_size, void* d_ws, size_t ws_size,
                              hipStream_t stream) {
  const float* x     = (const float*)d_in[0];
  const float* theta = (const float*)d_in[1];
  const float* W1    = (const float*)d_in[2];
  const float* b1    = (const float*)d_in[3];
  const float* W2    = (const float*)d_in[4];
  const float* b2    = (const float*)d_in[5];
  float* out = (float*)d_out;

  char* ws = (char*)d_ws;
  unsigned short* W2b = (unsigned short*)ws;                 // 2 MB bf16 swizzled
  float* W1t = (float*)(ws + (2u << 20));                    // 80 KB f32 transposed

  k_cvt_w2<<<(EMBED * FFN) / (256 * 8), 256, 0, stream>>>(W2, W2b);
  k_cvt_w1t<<<(NQ * FFN) / 256, 256, 0, stream>>>(W1, W1t);
  k_fused<<<(NTOK / BM) * (EMBED / BN), 512, 0, stream>>>(x, theta, W1t, b1, W2b, b2, out);
}

// Round 7
// 74.304 us; speedup vs baseline: 1.3483x; 1.1667x over previous
//
#include <hip/hip_runtime.h>
#include <hip/hip_bf16.h>

// QuantumFeedForward, fully fused, 4-phase schedule:
//   q[n,w] = prod_{v in M_w} cos(theta_v)*cos(x[n,v])   (analytic circuit collapse)
//   out    = relu(q@W1^T+b1) @ W2^T + b2
// H is generated ON the matrix pipe: H^T-tile = mfma(A=W1_aug frags, B=q_aug frags),
// bias folded as wire 10 (q_aug[10]=1, W1_aug[10][:]=b1), K padded to 32.
// W1f precomputed in exact A-fragment order; W2b CHUNK-SWIZZLED in global
// (chunk c of row r at (c&~7)|((c&7)^(r&7))) so linear global_load_lds gives
// conflict-free XOR-swizzled LDS tiles. Schedule: 4 phases/K-tile, raw barriers,
// lgkmcnt(0) per phase, one vmcnt(0) per K-tile (issue->drain ~3 phases).

typedef __attribute__((ext_vector_type(8))) short bf16x8;
typedef __attribute__((ext_vector_type(4))) float f32x4;
typedef __attribute__((ext_vector_type(8))) unsigned short us8;
typedef __attribute__((ext_vector_type(4))) unsigned short us4;

#define NTOK  16384
#define EMBED 512
#define FFN   2048
#define NQ    10
#define BM    256
#define BN    128
#define BK    64
#define NT    (FFN / BK)   // 32

__device__ __forceinline__ unsigned short f2bf(float f) {
  union { float f; unsigned int u; } a; a.f = f;
  unsigned int r = a.u + 0x7FFFu + ((a.u >> 16) & 1u);   // RNE
  return (unsigned short)(r >> 16);
}

__device__ __forceinline__ void gload_lds16(const void* g, void* l) {
  __builtin_amdgcn_global_load_lds(
      (const __attribute__((address_space(1))) unsigned int*)g,
      (__attribute__((address_space(3))) unsigned int*)l, 16, 0, 0);
}

// ---------------- K0: W2 (512x2048 f32) -> bf16, chunk-swizzled ----------------
__global__ __launch_bounds__(256) void k_cvt_w2(const float* __restrict__ W2,
                                                unsigned short* __restrict__ W2b) {
  int gid = blockIdx.x * 256 + threadIdx.x;     // one 16B chunk (8 f32 -> 8 bf16)
  int idx = gid * 8;
  int row = idx >> 11;                          // /2048
  int c   = (idx >> 3) & 255;                   // chunk within row
  int sc  = (c & ~7) | ((c & 7) ^ (row & 7));   // swizzled chunk
  float4 v0 = *(const float4*)(W2 + idx);
  float4 v1 = *(const float4*)(W2 + idx + 4);
  us8 o;
  o[0] = f2bf(v0.x); o[1] = f2bf(v0.y); o[2] = f2bf(v0.z); o[3] = f2bf(v0.w);
  o[4] = f2bf(v1.x); o[5] = f2bf(v1.y); o[6] = f2bf(v1.z); o[7] = f2bf(v1.w);
  *(us8*)(W2b + (size_t)row * FFN + sc * 8) = o;
}

// ---------------- K0b: W1_aug -> bf16 A-fragment order ----------------
// W1f[((kt*4 + j)*64 + lane)*8 + e] = W1aug[wire=(lane>>4)*8+e][k = kt*64+j*16+(lane&15)]
// W1aug[w][k] = W1[k][w] (w<10), b1[k] (w==10), 0 (w>10).  32 slices x 2048 bf16.
__global__ __launch_bounds__(256) void k_cvt_w1f(const float* __restrict__ W1,
                                                 const float* __restrict__ b1,
                                                 unsigned short* __restrict__ W1f) {
  int gid = blockIdx.x * 256 + threadIdx.x;   // 8192 = 32*4*64
  int l = gid & 63, j = (gid >> 6) & 3, kt = gid >> 8;
  int k_out = kt * 64 + j * 16 + (l & 15);
  int wg = (l >> 4) * 8;
  us8 o;
#pragma unroll
  for (int e = 0; e < 8; ++e) {
    int wire = wg + e;
    float v = (wire < NQ) ? W1[k_out * NQ + wire] : (wire == NQ ? b1[k_out] : 0.f);
    o[e] = f2bf(v);
  }
  *(us8*)(W1f + (size_t)gid * 8) = o;
}

// ---------------- K1: fused H-gen(MFMA) + GEMM, 4-phase ----------------
__global__ __launch_bounds__(512, 2) void k_fused(const float* __restrict__ x,
                                                  const float* __restrict__ theta,
                                                  const unsigned short* __restrict__ W1f_g,
                                                  const unsigned short* __restrict__ W2b,
                                                  const float* __restrict__ b2,
                                                  float* __restrict__ out) {
  __shared__ short Ah[2][BM * BK];     // 64KB: H tile, XOR-swizzled rows of 128B
  __shared__ short Bw[2][BN * BK];     // 32KB: W2 tile, swizzle from global layout
  __shared__ short W1fs[2][2048];      //  8KB: W1 A-frag slice, dist-2 prefetch

  // XCD-aware bijective swizzle: 256 blocks, 32 consecutive per XCD; n fastest.
  int bid = blockIdx.x;
  int swz = (bid & 7) * 32 + (bid >> 3);
  const int m0 = (swz >> 2) * BM;      // 64 m-tiles
  const int n0 = (swz & 3) * BN;       // 4 n-tiles
  const int tid  = threadIdx.x;
  const int lane = tid & 63;
  const int wave = tid >> 6;           // 8 waves: 4 (M) x 2 (N), 64x64 tiles
  const int wr = wave >> 1, wc = wave & 1;

  // ---- q_aug B-fragments for this wave's 4 token-tiles (rows wr*64..+63) ----
  bf16x8 qf[4];
  {
    const int masks[NQ] = {0x2AB,0x3FD,0x3FA,0x3F5,0x3EA,0x3D5,0x3AA,0x355,0x2AA,0x155};
    float cth[NQ];
#pragma unroll
    for (int w = 0; w < NQ; ++w) cth[w] = __builtin_cosf(theta[w]);
    const int g = lane >> 4;
#pragma unroll
    for (int t = 0; t < 4; ++t) {
      int tok = m0 + wr * 64 + t * 16 + (lane & 15);
      float z[NQ], qv[NQ];
#pragma unroll
      for (int w = 0; w < NQ; ++w)
        z[w] = __builtin_cosf(x[(size_t)tok * EMBED + w]) * cth[w];
#pragma unroll
      for (int w = 0; w < NQ; ++w) {
        float p = 1.f;
#pragma unroll
        for (int v = 0; v < NQ; ++v)
          if ((masks[w] >> v) & 1) p *= z[v];
        qv[w] = p;
      }
      bf16x8 f = (bf16x8)0;
      if (g == 0) {
        f[0]=(short)f2bf(qv[0]); f[1]=(short)f2bf(qv[1]); f[2]=(short)f2bf(qv[2]);
        f[3]=(short)f2bf(qv[3]); f[4]=(short)f2bf(qv[4]); f[5]=(short)f2bf(qv[5]);
        f[6]=(short)f2bf(qv[6]); f[7]=(short)f2bf(qv[7]);
      } else if (g == 1) {
        f[0]=(short)f2bf(qv[8]); f[1]=(short)f2bf(qv[9]); f[2]=(short)f2bf(1.f);
      }
      qf[t] = f;
    }
  }

  f32x4 acc[4][4] = {};
  bf16x8 wf[2];

#define STAGE_BW_CHUNK(KT, B, P)                                                \
  { int ch = (P) * 512 + tid; int row = ch >> 3, slot = ch & 7;                 \
    gload_lds16(&W2b[(size_t)(n0 + row) * FFN + (KT) * BK + slot * 8],          \
                &Bw[B][ch * 8]); }

#define STAGE_W1F(SL, B)                                                        \
  { if (tid < 256)                                                              \
      gload_lds16(&W1f_g[(size_t)(SL) * 2048 + tid * 8], &W1fs[B][tid * 8]); }

#define LOAD_WF(WB)                                                             \
  { wf[0] = *(const bf16x8*)&W1fs[WB][((2 * wc + 0) * 64 + lane) * 8];          \
    wf[1] = *(const bf16x8*)&W1fs[WB][((2 * wc + 1) * 64 + lane) * 8]; }

  // H^T-tile: D[k][token]; col=token=lane&15, row(k-local)=(lane>>4)*4+r.
#define HGEN_TO(DB)                                                             \
  {                                                                             \
    _Pragma("unroll")                                                           \
    for (int t = 0; t < 4; ++t) {                                               \
      _Pragma("unroll")                                                         \
      for (int j2 = 0; j2 < 2; ++j2) {                                          \
        f32x4 zz = {};                                                          \
        f32x4 d = __builtin_amdgcn_mfma_f32_16x16x32_bf16(wf[j2], qf[t], zz, 0, 0, 0); \
        d = __builtin_elementwise_max(d, zz);                                   \
        us4 o;                                                                  \
        o[0]=f2bf(d[0]); o[1]=f2bf(d[1]); o[2]=f2bf(d[2]); o[3]=f2bf(d[3]);     \
        int token = wr * 64 + t * 16 + (lane & 15);                             \
        int jg = 2 * wc + j2;                                                   \
        int chunk = jg * 2 + ((lane >> 4) >> 1);                                \
        int sub = ((lane >> 4) & 1) * 4;                                        \
        *(us4*)&Ah[DB][token * BK + ((chunk ^ (token & 7))) * 8 + sub] = o;     \
      }                                                                         \
    }                                                                           \
  }

#define READ_AF(DST, CB, I, KK)                                                 \
  { int row = wr * 64 + (I) * 16 + (lane & 15);                                 \
    DST = *(const bf16x8*)&Ah[CB][row * BK + (((KK) * 4 + (lane >> 4)) ^ (row & 7)) * 8]; }

#define READ_BG(CB, KK)                                                         \
  { _Pragma("unroll")                                                           \
    for (int jj = 0; jj < 4; ++jj) {                                            \
      int row = wc * 64 + jj * 16 + (lane & 15);                                \
      bg[jj] = *(const bf16x8*)&Bw[CB][row * BK + (((KK) * 4 + (lane >> 4)) ^ (row & 7)) * 8]; } }

#define MFMA8(IP)                                                               \
  __builtin_amdgcn_s_setprio(1);                                                \
  _Pragma("unroll")                                                             \
  for (int jj = 0; jj < 4; ++jj) {                                              \
    acc[(IP)][jj]     = __builtin_amdgcn_mfma_f32_16x16x32_bf16(af0, bg[jj], acc[(IP)][jj], 0, 0, 0);     \
    acc[(IP) + 1][jj] = __builtin_amdgcn_mfma_f32_16x16x32_bf16(af1, bg[jj], acc[(IP) + 1][jj], 0, 0, 0); \
  }                                                                             \
  __builtin_amdgcn_s_setprio(0);

#define FENCE  asm volatile("" ::: "memory")
#define BAR    __builtin_amdgcn_s_barrier()
#define LGKM0  asm volatile("s_waitcnt lgkmcnt(0)" ::: "memory");               \
               __builtin_amdgcn_sched_barrier(0)

  // ---- prologue: stage slice0->W1fs[1], slice1->W1fs[0], Bw(0)->buf0; H(0)->Ah[0]
  STAGE_W1F(0, 1);
  STAGE_W1F(1, 0);
  STAGE_BW_CHUNK(0, 0, 0);
  STAGE_BW_CHUNK(0, 0, 1);
  __syncthreads();             // full drain: staged data ready
  LOAD_WF(1);
  HGEN_TO(0);
  __syncthreads();             // Ah[0] ready

  // ---- main loop: 4 phases per K-tile ----
  for (int kt = 0; kt < NT; ++kt) {
    const int cur = kt & 1, nxt = cur ^ 1;
    const bool hasN  = (kt + 1 < NT);
    const bool hasN2 = (kt + 2 < NT);
    bf16x8 bg[4];
    // ---- P0: kk0, i={0,1}; stage Bw chunk0(kt+1) ----
    {
      bf16x8 af0, af1;
      READ_AF(af0, cur, 0, 0); READ_AF(af1, cur, 1, 0);
      READ_BG(cur, 0);
      if (hasN) STAGE_BW_CHUNK(kt + 1, nxt, 0);
      FENCE; BAR; LGKM0;
      MFMA8(0);
      FENCE; BAR;
    }
    // ---- P1: kk0, i={2,3}; stage Bw chunk1(kt+1) ----
    {
      bf16x8 af0, af1;
      READ_AF(af0, cur, 2, 0); READ_AF(af1, cur, 3, 0);
      if (hasN) STAGE_BW_CHUNK(kt + 1, nxt, 1);
      FENCE; BAR; LGKM0;
      MFMA8(2);
      FENCE; BAR;
    }
    // ---- P2: kk1, i={0,1}; stage W1f(kt+2); load wf (slice kt+1) ----
    {
      bf16x8 af0, af1;
      READ_AF(af0, cur, 0, 1); READ_AF(af1, cur, 1, 1);
      READ_BG(cur, 1);
      if (hasN2) STAGE_W1F(kt + 2, nxt);
      if (hasN)  LOAD_WF(cur);
      FENCE; BAR; LGKM0;
      MFMA8(0);
      FENCE; BAR;
    }
    // ---- P3: kk1, i={2,3}; HGEN H(kt+1)->Ah[nxt]; drain vmcnt ----
    {
      bf16x8 af0, af1;
      READ_AF(af0, cur, 2, 1); READ_AF(af1, cur, 3, 1);
      if (hasN) HGEN_TO(nxt);
      FENCE; BAR; LGKM0;
      MFMA8(2);
      asm volatile("s_waitcnt vmcnt(0)" ::: "memory");   // Bw/W1f for kt+1/kt+2 landed
      FENCE; BAR;
    }
  }

  // ---- epilogue: out = acc + b2 ----
#pragma unroll
  for (int i = 0; i < 4; ++i) {
    const int row = m0 + wr * 64 + i * 16 + (lane >> 4) * 4;
#pragma unroll
    for (int jj = 0; jj < 4; ++jj) {
      const int col = n0 + wc * 64 + jj * 16 + (lane & 15);
      const float bbv = b2[col];
#pragma unroll
      for (int r = 0; r < 4; ++r)
        out[(size_t)(row + r) * EMBED + col] = acc[i][jj][r] + bbv;
    }
  }
#undef STAGE_BW_CHUNK
#undef STAGE_W1F
#undef LOAD_WF
#undef HGEN_TO
#undef READ_AF
#undef READ_BG
#undef MFMA8
#undef FENCE
#undef BAR
#undef LGKM0
}

extern "C" void kernel_launch(void* const* d_in, const int* in_sizes, int n_in,
                              void* d_out, int out_size, void* d_ws, size_t ws_size,
                              hipStream_t stream) {
  const float* x     = (const float*)d_in[0];
  const float* theta = (const float*)d_in[1];
  const float* W1    = (const float*)d_in[2];
  const float* b1    = (const float*)d_in[3];
  const float* W2    = (const float*)d_in[4];
  const float* b2    = (const float*)d_in[5];
  float* out = (float*)d_out;

  char* ws = (char*)d_ws;
  unsigned short* W2b  = (unsigned short*)ws;                 // 2 MB bf16 swizzled
  unsigned short* W1fg = (unsigned short*)(ws + (2u << 20));  // 128 KB bf16 A-frags

  k_cvt_w2 <<<(EMBED * FFN) / (256 * 8), 256, 0, stream>>>(W2, W2b);
  k_cvt_w1f<<<32, 256, 0, stream>>>(W1, b1, W1fg);
  k_fused  <<<(NTOK / BM) * (EMBED / BN), 512, 0, stream>>>(x, theta, W1fg, W2b, b2, out);
}

// Round 8
// 59.674 us; speedup vs baseline: 1.6788x; 1.2452x over previous
//
#include <hip/hip_runtime.h>
#include <hip/hip_bf16.h>

// QuantumFeedForward, fully fused:
//   q[n,w] = prod_{v in M_w} cos(theta_v)*cos(x[n,v])   (analytic circuit collapse)
//   out    = relu(q@W1^T+b1) @ W2^T + b2
// H generated on the matrix pipe: H^T-tile = mfma(A=W1_aug frag, B=q_aug frag),
// bias folded as wire 10. q_aug B-frags precomputed by k_q (packed global);
// W1_aug A-frags precomputed by k_cvt_w1f; W2b CHUNK-SWIZZLED in global
// (chunk c of row r at (c&~7)|((c&7)^(r&7))) so linear global_load_lds gives
// conflict-free XOR-swizzled LDS tiles.
// Schedule: 256-thread blocks (4 waves, 64x64 tiles), 2 blocks/CU (64KB LDS),
// 2 fat phases per K-tile (16 MFMA each), W1-frags register-prefetched dist-2.

typedef __attribute__((ext_vector_type(8))) short bf16x8;
typedef __attribute__((ext_vector_type(4))) float f32x4;
typedef __attribute__((ext_vector_type(8))) unsigned short us8;
typedef __attribute__((ext_vector_type(4))) unsigned short us4;

#define NTOK  16384
#define EMBED 512
#define FFN   2048
#define NQ    10
#define BM    128
#define BN    128
#define BK    64
#define NT    (FFN / BK)   // 32

__device__ __forceinline__ unsigned short f2bf(float f) {
  union { float f; unsigned int u; } a; a.f = f;
  unsigned int r = a.u + 0x7FFFu + ((a.u >> 16) & 1u);   // RNE
  return (unsigned short)(r >> 16);
}

__device__ __forceinline__ void gload_lds16(const void* g, void* l) {
  __builtin_amdgcn_global_load_lds(
      (const __attribute__((address_space(1))) unsigned int*)g,
      (__attribute__((address_space(3))) unsigned int*)l, 16, 0, 0);
}

// ---------------- K0: W2 (512x2048 f32) -> bf16, chunk-swizzled ----------------
__global__ __launch_bounds__(256) void k_cvt_w2(const float* __restrict__ W2,
                                                unsigned short* __restrict__ W2b) {
  int gid = blockIdx.x * 256 + threadIdx.x;
  int idx = gid * 8;
  int row = idx >> 11;
  int c   = (idx >> 3) & 255;
  int sc  = (c & ~7) | ((c & 7) ^ (row & 7));
  float4 v0 = *(const float4*)(W2 + idx);
  float4 v1 = *(const float4*)(W2 + idx + 4);
  us8 o;
  o[0] = f2bf(v0.x); o[1] = f2bf(v0.y); o[2] = f2bf(v0.z); o[3] = f2bf(v0.w);
  o[4] = f2bf(v1.x); o[5] = f2bf(v1.y); o[6] = f2bf(v1.z); o[7] = f2bf(v1.w);
  *(us8*)(W2b + (size_t)row * FFN + sc * 8) = o;
}

// ---------------- K0b: W1_aug -> bf16 A-fragment order ----------------
// W1f[((kt*4+j)*64+lane)*8+e] = W1aug[wire=(lane>>4)*8+e][k = kt*64+j*16+(lane&15)]
__global__ __launch_bounds__(256) void k_cvt_w1f(const float* __restrict__ W1,
                                                 const float* __restrict__ b1,
                                                 unsigned short* __restrict__ W1f) {
  int gid = blockIdx.x * 256 + threadIdx.x;   // 8192 = 32*4*64
  int l = gid & 63, j = (gid >> 6) & 3, kt = gid >> 8;
  int k_out = kt * 64 + j * 16 + (l & 15);
  int wg = (l >> 4) * 8;
  us8 o;
#pragma unroll
  for (int e = 0; e < 8; ++e) {
    int wire = wg + e;
    float v = (wire < NQ) ? W1[k_out * NQ + wire] : (wire == NQ ? b1[k_out] : 0.f);
    o[e] = f2bf(v);
  }
  *(us8*)(W1f + (size_t)gid * 8) = o;
}

// ---------------- K0c: q_aug B-fragments, packed ----------------
// Qf[(tile*64+l)*8+e] = qaug[wire=(l>>4)*8+e][token = tile*16 + (l&15)]
__global__ __launch_bounds__(256) void k_q(const float* __restrict__ x,
                                           const float* __restrict__ theta,
                                           unsigned short* __restrict__ Qf) {
  int gid = blockIdx.x * 256 + threadIdx.x;   // 65536 = 1024 tiles * 64 lanes
  int l = gid & 63, tile = gid >> 6;
  int tok = tile * 16 + (l & 15), g = l >> 4;
  const int masks[NQ] = {0x2AB,0x3FD,0x3FA,0x3F5,0x3EA,0x3D5,0x3AA,0x355,0x2AA,0x155};
  float z[NQ], qv[NQ];
#pragma unroll
  for (int w = 0; w < NQ; ++w)
    z[w] = __builtin_cosf(x[(size_t)tok * EMBED + w]) * __builtin_cosf(theta[w]);
#pragma unroll
  for (int w = 0; w < NQ; ++w) {
    float p = 1.f;
#pragma unroll
    for (int v = 0; v < NQ; ++v)
      if ((masks[w] >> v) & 1) p *= z[v];
    qv[w] = p;
  }
  us8 o = (us8)0;
  if (g == 0) {
#pragma unroll
    for (int e = 0; e < 8; ++e) o[e] = f2bf(qv[e]);
  } else if (g == 1) {
    o[0] = f2bf(qv[8]); o[1] = f2bf(qv[9]); o[2] = f2bf(1.f);
  }
  *(us8*)(Qf + (size_t)gid * 8) = o;
}

// ---------------- K1: fused H-gen(MFMA) + GEMM ----------------
__global__ __launch_bounds__(256, 2) void k_fused(const unsigned short* __restrict__ Qf,
                                                  const unsigned short* __restrict__ W1f_g,
                                                  const unsigned short* __restrict__ W2b,
                                                  const float* __restrict__ b2,
                                                  float* __restrict__ out) {
  __shared__ short Ah[2][BM * BK];     // 32KB: H tile, XOR-swizzled rows of 128B
  __shared__ short Bw[2][BN * BK];     // 32KB: W2 tile, swizzle from global layout

  // XCD-aware bijective swizzle: 512 blocks, 64 consecutive per XCD; n fastest.
  int bid = blockIdx.x;
  int swz = (bid & 7) * 64 + (bid >> 3);
  const int m0 = (swz >> 2) * BM;      // 128 m-tiles
  const int n0 = (swz & 3) * BN;       // 4 n-tiles
  const int tid  = threadIdx.x;
  const int lane = tid & 63;
  const int wave = tid >> 6;           // 4 waves: 2 (M) x 2 (N), 64x64 tiles
  const int wm = wave >> 1, wn = wave & 1;

  // q_aug B-frags for this wave's 4 token-tiles (precomputed, 4 x b128)
  bf16x8 qf[4];
#pragma unroll
  for (int t = 0; t < 4; ++t)
    qf[t] = *(const bf16x8*)&Qf[((size_t)((m0 >> 4) + wm * 4 + t) * 64 + lane) * 8];

  f32x4 acc[4][4] = {};
  bf16x8 wfA0, wfA1, wfB0, wfB1;       // W1 A-frag slices, dist-2 reg prefetch

#define WLOADF(D0, D1, SL)                                                      \
  { D0 = *(const bf16x8*)&W1f_g[(((size_t)(SL) * 4 + 2 * wn + 0) * 64 + lane) * 8]; \
    D1 = *(const bf16x8*)&W1f_g[(((size_t)(SL) * 4 + 2 * wn + 1) * 64 + lane) * 8]; }

#define STAGE_BW(KT, B, P)                                                      \
  { int ch = (P) * 256 + tid; int row = ch >> 3, slot = ch & 7;                 \
    gload_lds16(&W2b[(size_t)(n0 + row) * FFN + (KT) * BK + slot * 8],          \
                &Bw[B][ch * 8]); }

#define READ_AF(DST, CB, I, KK)                                                 \
  { int row = wm * 64 + (I) * 16 + (lane & 15);                                 \
    DST = *(const bf16x8*)&Ah[CB][row * BK + (((KK) * 4 + (lane >> 4)) ^ (row & 7)) * 8]; }

#define READ_BG(DST, CB, J, KK)                                                 \
  { int row = wn * 64 + (J) * 16 + (lane & 15);                                 \
    DST = *(const bf16x8*)&Bw[CB][row * BK + (((KK) * 4 + (lane >> 4)) ^ (row & 7)) * 8]; }

#define HGEN1(F, T, JG, DB)                                                     \
  { f32x4 zz = {};                                                              \
    f32x4 d = __builtin_amdgcn_mfma_f32_16x16x32_bf16((F), qf[T], zz, 0, 0, 0); \
    d = __builtin_elementwise_max(d, zz);                                       \
    __hip_bfloat16 c0 = __float2bfloat16(d[0]), c1 = __float2bfloat16(d[1]);    \
    __hip_bfloat16 c2 = __float2bfloat16(d[2]), c3 = __float2bfloat16(d[3]);    \
    us4 o;                                                                      \
    o[0] = *(unsigned short*)&c0; o[1] = *(unsigned short*)&c1;                 \
    o[2] = *(unsigned short*)&c2; o[3] = *(unsigned short*)&c3;                 \
    int token = wm * 64 + (T) * 16 + (lane & 15);                               \
    int chunk = (JG) * 2 + ((lane >> 4) >> 1);                                  \
    *(us4*)&Ah[DB][token * BK + ((chunk ^ (token & 7))) * 8 + ((lane >> 4) & 1) * 4] = o; }

#define HGEN(F0, F1, DB)                                                        \
  { _Pragma("unroll")                                                           \
    for (int t = 0; t < 4; ++t) { HGEN1(F0, t, 2 * wn + 0, DB); HGEN1(F1, t, 2 * wn + 1, DB); } }

#define MFMA16()                                                                \
  __builtin_amdgcn_s_setprio(1);                                                \
  acc[0][0] = __builtin_amdgcn_mfma_f32_16x16x32_bf16(af0, bg0, acc[0][0], 0, 0, 0); \
  acc[0][1] = __builtin_amdgcn_mfma_f32_16x16x32_bf16(af0, bg1, acc[0][1], 0, 0, 0); \
  acc[0][2] = __builtin_amdgcn_mfma_f32_16x16x32_bf16(af0, bg2, acc[0][2], 0, 0, 0); \
  acc[0][3] = __builtin_amdgcn_mfma_f32_16x16x32_bf16(af0, bg3, acc[0][3], 0, 0, 0); \
  acc[1][0] = __builtin_amdgcn_mfma_f32_16x16x32_bf16(af1, bg0, acc[1][0], 0, 0, 0); \
  acc[1][1] = __builtin_amdgcn_mfma_f32_16x16x32_bf16(af1, bg1, acc[1][1], 0, 0, 0); \
  acc[1][2] = __builtin_amdgcn_mfma_f32_16x16x32_bf16(af1, bg2, acc[1][2], 0, 0, 0); \
  acc[1][3] = __builtin_amdgcn_mfma_f32_16x16x32_bf16(af1, bg3, acc[1][3], 0, 0, 0); \
  acc[2][0] = __builtin_amdgcn_mfma_f32_16x16x32_bf16(af2, bg0, acc[2][0], 0, 0, 0); \
  acc[2][1] = __builtin_amdgcn_mfma_f32_16x16x32_bf16(af2, bg1, acc[2][1], 0, 0, 0); \
  acc[2][2] = __builtin_amdgcn_mfma_f32_16x16x32_bf16(af2, bg2, acc[2][2], 0, 0, 0); \
  acc[2][3] = __builtin_amdgcn_mfma_f32_16x16x32_bf16(af2, bg3, acc[2][3], 0, 0, 0); \
  acc[3][0] = __builtin_amdgcn_mfma_f32_16x16x32_bf16(af3, bg0, acc[3][0], 0, 0, 0); \
  acc[3][1] = __builtin_amdgcn_mfma_f32_16x16x32_bf16(af3, bg1, acc[3][1], 0, 0, 0); \
  acc[3][2] = __builtin_amdgcn_mfma_f32_16x16x32_bf16(af3, bg2, acc[3][2], 0, 0, 0); \
  acc[3][3] = __builtin_amdgcn_mfma_f32_16x16x32_bf16(af3, bg3, acc[3][3], 0, 0, 0); \
  __builtin_amdgcn_s_setprio(0);

#define FENCE  asm volatile("" ::: "memory")
#define BAR    __builtin_amdgcn_s_barrier()
#define LGKM0  asm volatile("s_waitcnt lgkmcnt(0)" ::: "memory");               \
               __builtin_amdgcn_sched_barrier(0)

#define BODY(KT, FU0, FU1, FL0, FL1)                                            \
  {                                                                             \
    const int cur = (KT) & 1, nxt = cur ^ 1;                                    \
    const bool hasN = (KT) + 1 < NT, hasN2 = (KT) + 2 < NT;                     \
    bf16x8 af0, af1, af2, af3, bg0, bg1, bg2, bg3;                              \
    /* ---- P0: kk=0 ---- */                                                    \
    if (hasN2) { WLOADF(FL0, FL1, (KT) + 2); }                                  \
    READ_AF(af0, cur, 0, 0); READ_AF(af1, cur, 1, 0);                           \
    READ_AF(af2, cur, 2, 0); READ_AF(af3, cur, 3, 0);                           \
    READ_BG(bg0, cur, 0, 0); READ_BG(bg1, cur, 1, 0);                           \
    READ_BG(bg2, cur, 2, 0); READ_BG(bg3, cur, 3, 0);                           \
    if (hasN) { STAGE_BW((KT) + 1, nxt, 0); STAGE_BW((KT) + 1, nxt, 1); }       \
    FENCE; BAR; LGKM0;                                                          \
    MFMA16();                                                                   \
    FENCE; BAR;                                                                 \
    /* ---- P1: kk=1 ---- */                                                    \
    READ_AF(af0, cur, 0, 1); READ_AF(af1, cur, 1, 1);                           \
    READ_AF(af2, cur, 2, 1); READ_AF(af3, cur, 3, 1);                           \
    READ_BG(bg0, cur, 0, 1); READ_BG(bg1, cur, 1, 1);                           \
    READ_BG(bg2, cur, 2, 1); READ_BG(bg3, cur, 3, 1);                           \
    if (hasN) { STAGE_BW((KT) + 1, nxt, 2); STAGE_BW((KT) + 1, nxt, 3);         \
                HGEN(FU0, FU1, nxt); }                                          \
    FENCE; BAR; LGKM0;                                                          \
    MFMA16();                                                                   \
    asm volatile("s_waitcnt vmcnt(0)" ::: "memory");                            \
    FENCE; BAR;                                                                 \
  }

  // ---- prologue: W1 slices 0,1 -> regs; Bw(0); H(0) -> Ah[0] ----
  WLOADF(wfB0, wfB1, 0);
  WLOADF(wfA0, wfA1, 1);
  STAGE_BW(0, 0, 0); STAGE_BW(0, 0, 1); STAGE_BW(0, 0, 2); STAGE_BW(0, 0, 3);
  __syncthreads();             // full drain: Bw[0] + wf regs ready
  HGEN(wfB0, wfB1, 0);         // Ah[0]
  __syncthreads();             // HGEN writes drained + visible

  // ---- main loop: 2 K-tiles per iteration (static wf parity) ----
  for (int kt = 0; kt < NT; kt += 2) {
    BODY(kt,     wfA0, wfA1, wfB0, wfB1);   // even: use A (slice kt+1), load B (kt+2)
    BODY(kt + 1, wfB0, wfB1, wfA0, wfA1);   // odd:  use B, load A
  }

  // ---- epilogue: out = acc + b2 ----
#pragma unroll
  for (int i = 0; i < 4; ++i) {
    const int row = m0 + wm * 64 + i * 16 + (lane >> 4) * 4;
#pragma unroll
    for (int j = 0; j < 4; ++j) {
      const int col = n0 + wn * 64 + j * 16 + (lane & 15);
      const float bbv = b2[col];
#pragma unroll
      for (int r = 0; r < 4; ++r)
        out[(size_t)(row + r) * EMBED + col] = acc[i][j][r] + bbv;
    }
  }
#undef WLOADF
#undef STAGE_BW
#undef READ_AF
#undef READ_BG
#undef HGEN1
#undef HGEN
#undef MFMA16
#undef FENCE
#undef BAR
#undef LGKM0
#undef BODY
}

extern "C" void kernel_launch(void* const* d_in, const int* in_sizes, int n_in,
                              void* d_out, int out_size, void* d_ws, size_t ws_size,
                              hipStream_t stream) {
  const float* x     = (const float*)d_in[0];
  const float* theta = (const float*)d_in[1];
  const float* W1    = (const float*)d_in[2];
  const float* b1    = (const float*)d_in[3];
  const float* W2    = (const float*)d_in[4];
  const float* b2    = (const float*)d_in[5];
  float* out = (float*)d_out;

  char* ws = (char*)d_ws;
  unsigned short* W2b  = (unsigned short*)ws;                          // 2 MB
  unsigned short* W1fg = (unsigned short*)(ws + (2u << 20));           // 128 KB
  unsigned short* Qfg  = (unsigned short*)(ws + (2u << 20) + (128u << 10)); // 1 MB

  k_cvt_w2 <<<(EMBED * FFN) / (256 * 8), 256, 0, stream>>>(W2, W2b);
  k_cvt_w1f<<<32, 256, 0, stream>>>(W1, b1, W1fg);
  k_q      <<<256, 256, 0, stream>>>(x, theta, Qfg);
  k_fused  <<<(NTOK / BM) * (EMBED / BN), 256, 0, stream>>>(Qfg, W1fg, W2b, b2, out);
}